// Round 1
// baseline (327.338 us; speedup 1.0000x reference)
//
#include <hip/hip_runtime.h>

// B=4, H=8, Nt=Nc=2048, D=512, E=64, scale = 1/64 folded into Wq at cast.
#define B_   4
#define H_   8
#define NSEQ 2048
#define D_   512
#define E_   64

typedef __bf16 bf16x8 __attribute__((ext_vector_type(8)));
typedef float  f32x4  __attribute__((ext_vector_type(4)));

__device__ __forceinline__ unsigned short f2b(float f) {
    __bf16 h = (__bf16)f;                     // RNE
    return __builtin_bit_cast(unsigned short, h);
}
__device__ __forceinline__ bf16x8 ld_frag(const unsigned short* p) {
    return *reinterpret_cast<const bf16x8*>(p);
}
// wave-private LDS write->read ordering (DS ops from one wave execute in order;
// the waitcnt just ensures data arrival before dependent ds_read issue result use)
__device__ __forceinline__ void wave_lds_fence() {
    __asm__ __volatile__("s_waitcnt lgkmcnt(0)" ::: "memory");
}

// ---------------------------------------------------------------------------
// Cast + transpose W: [H][D][E] fp32 -> [he][d] bf16 (y=0..2); Wout (y=3).
// Wq (y=2) pre-scaled by 1/64 (exact exponent shift).
// ---------------------------------------------------------------------------
__global__ __launch_bounds__(256)
void cast_w_kernel(const float* __restrict__ Wk, const float* __restrict__ Wv,
                   const float* __restrict__ Wq, const float* __restrict__ Wo,
                   unsigned short* __restrict__ okt, unsigned short* __restrict__ ovt,
                   unsigned short* __restrict__ oqt, unsigned short* __restrict__ oo) {
    int idx = blockIdx.x * 256 + threadIdx.x;   // < 262144
    int y = blockIdx.y;
    if (y == 3) { oo[idx] = f2b(Wo[idx]); return; }
    const float* src = y == 0 ? Wk : (y == 1 ? Wv : Wq);
    unsigned short* dst = y == 0 ? okt : (y == 1 ? ovt : oqt);
    float scl = (y == 2) ? 0.015625f : 1.0f;
    int hh = idx >> 15, rem = idx & 32767, d = rem >> 6, e = rem & 63;
    dst[hh * 32768 + e * 512 + d] = f2b(src[idx] * scl);   // [(h*64+e)][d]
}

// ---------------------------------------------------------------------------
// Projection NT-GEMM: C[m][he] = sum_d X[m][d] * Wt[he][d]. 8192x512x512.
// 128x64 tile, BK=64, double-buffered LDS, ONE barrier per K-iter.
// Cross-iteration pipeline: loads issued at iter j are committed at j+1.
// which: 0=Q 1=K 2=V. Fused fp32->bf16 cast of X at commit.
// ---------------------------------------------------------------------------
__global__ __launch_bounds__(256, 2)
void proj_gemm(const float* __restrict__ query, const float* __restrict__ keys,
               const float* __restrict__ values,
               const unsigned short* __restrict__ wqt,
               const unsigned short* __restrict__ wkt,
               const unsigned short* __restrict__ wvt,
               unsigned short* __restrict__ qb, unsigned short* __restrict__ kb,
               unsigned short* __restrict__ vtb) {
    const int m0  = blockIdx.x * 128;
    const int no0 = blockIdx.y * 64;
    const int which = blockIdx.z;
    const int tid = threadIdx.x;
    const int wave = tid >> 6, lane = tid & 63;
    const int quad = lane >> 4, l16 = lane & 15;

    const float* X = which == 0 ? query : (which == 1 ? keys : values);
    const unsigned short* W = which == 0 ? wqt : (which == 1 ? wkt : wvt);

    __shared__ unsigned short Ab[2][128][72];   // 36.9 KB
    __shared__ unsigned short Bb[2][64][72];    // 18.4 KB

    const float* Xp = X + (size_t)m0 * D_;
    const unsigned short* Wp = W + (size_t)no0 * D_;

    float4 aF[8]; uint4 bU[2];
    // A: 128 rows x 16 float4 (BK=64) ; B: 64 rows x 8 uint4
    #define PROJ_LOAD(k0)                                                      \
        {   _Pragma("unroll")                                                  \
            for (int i = 0; i < 8; ++i) {                                      \
                int idx = tid + i * 256;                                       \
                aF[i] = *reinterpret_cast<const float4*>(                      \
                    Xp + (size_t)(idx >> 4) * D_ + (k0) + (idx & 15) * 4);     \
            }                                                                  \
            _Pragma("unroll")                                                  \
            for (int i = 0; i < 2; ++i) {                                      \
                int idx = tid + i * 256;                                       \
                bU[i] = *reinterpret_cast<const uint4*>(                       \
                    Wp + (size_t)(idx >> 3) * D_ + (k0) + (idx & 7) * 8);      \
            } }
    #define PROJ_COMMIT(buf)                                                   \
        {   _Pragma("unroll")                                                  \
            for (int i = 0; i < 8; ++i) {                                      \
                int idx = tid + i * 256;                                       \
                ushort4 o = make_ushort4(f2b(aF[i].x), f2b(aF[i].y),           \
                                         f2b(aF[i].z), f2b(aF[i].w));          \
                *reinterpret_cast<ushort4*>(&Ab[buf][idx >> 4][(idx & 15) * 4]) = o; \
            }                                                                  \
            _Pragma("unroll")                                                  \
            for (int i = 0; i < 2; ++i) {                                      \
                int idx = tid + i * 256;                                       \
                *reinterpret_cast<uint4*>(&Bb[buf][idx >> 3][(idx & 7) * 8]) = bU[i]; \
            } }

    PROJ_LOAD(0)
    PROJ_COMMIT(0)
    PROJ_LOAD(64)
    __syncthreads();

    const f32x4 z = {0.f, 0.f, 0.f, 0.f};
    f32x4 acc[2][4];
    #pragma unroll
    for (int i = 0; i < 2; ++i)
        #pragma unroll
        for (int j = 0; j < 4; ++j) acc[i][j] = z;

    for (int kt = 0; kt < 8; ++kt) {
        const int cur = kt & 1;
        #pragma unroll
        for (int kk = 0; kk < 2; ++kk) {
            bf16x8 bfr[4];
            #pragma unroll
            for (int nt = 0; nt < 4; ++nt)
                bfr[nt] = ld_frag(&Bb[cur][nt * 16 + l16][kk * 32 + quad * 8]);
            #pragma unroll
            for (int mt = 0; mt < 2; ++mt) {
                bf16x8 af = ld_frag(&Ab[cur][wave * 32 + mt * 16 + l16][kk * 32 + quad * 8]);
                #pragma unroll
                for (int nt = 0; nt < 4; ++nt)
                    acc[mt][nt] = __builtin_amdgcn_mfma_f32_16x16x32_bf16(
                        af, bfr[nt], acc[mt][nt], 0, 0, 0);
            }
        }
        if (kt < 7) {
            PROJ_COMMIT(1 - cur)               // tile kt+1 (loaded last iter)
            if (kt + 2 < 8) PROJ_LOAD((kt + 2) * 64)
        }
        __syncthreads();                        // single barrier per iter
    }

    // epilogue: reuse Ab as staging
    if (which != 2) {
        unsigned short (*Os)[72] = reinterpret_cast<unsigned short(*)[72]>(&Ab[0][0][0]);
        #pragma unroll
        for (int mt = 0; mt < 2; ++mt)
            #pragma unroll
            for (int nt = 0; nt < 4; ++nt)
                #pragma unroll
                for (int r = 0; r < 4; ++r)
                    Os[wave * 32 + mt * 16 + quad * 4 + r][nt * 16 + l16] =
                        f2b(acc[mt][nt][r]);
        __syncthreads();
        unsigned short* Y = (which == 0 ? qb : kb);
        #pragma unroll
        for (int i = 0; i < 4; ++i) {           // 128 rows x 8 uint4
            int idx = tid + i * 256;
            int row = idx >> 3, seg = idx & 7;
            *reinterpret_cast<uint4*>(Y + (size_t)(m0 + row) * D_ + no0 + seg * 8) =
                *reinterpret_cast<const uint4*>(&Os[row][seg * 8]);
        }
    } else {
        unsigned short (*Ot)[136] = reinterpret_cast<unsigned short(*)[136]>(&Ab[0][0][0]);
        #pragma unroll
        for (int mt = 0; mt < 2; ++mt)
            #pragma unroll
            for (int nt = 0; nt < 4; ++nt) {
                ushort4 o = make_ushort4(f2b(acc[mt][nt][0]), f2b(acc[mt][nt][1]),
                                         f2b(acc[mt][nt][2]), f2b(acc[mt][nt][3]));
                *reinterpret_cast<ushort4*>(
                    &Ot[nt * 16 + l16][wave * 32 + mt * 16 + quad * 4]) = o;
            }
        __syncthreads();
        const int b = m0 >> 11, nloc = m0 & 2047;
        #pragma unroll
        for (int i = 0; i < 4; ++i) {           // 64 he-rows x 16 uint4
            int idx = tid + i * 256;
            int lhe = idx >> 4, seg = idx & 15;
            int ghe = no0 + lhe;                 // h = ghe>>6, e = ghe&63
            *reinterpret_cast<uint4*>(
                vtb + ((size_t)(b * H_ + (ghe >> 6)) * E_ + (ghe & 63)) * NSEQ +
                nloc + seg * 8) =
                *reinterpret_cast<const uint4*>(&Ot[lhe][seg * 8]);
        }
    }
    #undef PROJ_LOAD
    #undef PROJ_COMMIT
}

// ---------------------------------------------------------------------------
// Flash attention, transposed-S, 64-row Q tiles (grid 1024), K/V double-
// buffered LDS, ONE barrier per 64-key iter. Wave = 16 Q-rows.
//   St = K·Q^T ; P = exp(St) via wave-private LDS ; O^T = V^T·P^T.
// m=0 softmax (|s| bounded by construction), deferred l-reduction.
//
// Occupancy restructure vs previous version:
//  - 64x64 unpadded tiles, 128-B rows, XOR swizzle byte^=(row&7)<<4 on the
//    16B slot (kills the stride-128B ds_read_b128 bank conflicts).
//  - P staged in the STALE K double-buffer half (Ks[1-cur]) instead of a
//    dedicated Ps array. Safe because each wave only touches its OWN rows:
//    commit is remapped so wave w owns rows [16w,16w+16) of K and V tiles,
//    matching the wave-private P rows (wave*16+l16). Same-wave DS ordering
//    + lgkmcnt fence covers W->R; the barrier covers buffer flips.
//  - LDS = 32 KiB -> 4 blocks/CU; grid 1024 = 256 CU x 4 all-resident,
//    zero dispatch tail (was 3/CU: 768-block round + 256-block tail round).
// ---------------------------------------------------------------------------
__global__ __launch_bounds__(256, 4)
void attn_kernel(const unsigned short* __restrict__ qbp,
                 const unsigned short* __restrict__ kbp,
                 const unsigned short* __restrict__ vtbp,
                 unsigned short* __restrict__ aob) {
    const int L = blockIdx.x;
    const int bh = L & 31, qt = L >> 5;      // L%8 pattern -> XCD K/V affinity
    const int b = bh >> 3, h = bh & 7;
    const int n0 = qt * 64;
    const int tid = threadIdx.x;
    const int wave = tid >> 6, lane = tid & 63;
    const int quad = lane >> 4, l16 = lane & 15;

    __shared__ unsigned short Ks[2][64 * 64];  // 16 KiB (dbuf K, 128-B rows)
    __shared__ unsigned short Vs[2][64 * 64];  // 16 KiB (dbuf V^T)

    const unsigned short* kbase = kbp + (size_t)(b * NSEQ) * D_ + h * 64;
    const unsigned short* vbase = vtbp + (size_t)(b * H_ + h) * E_ * NSEQ;

    const int swzF = (l16 & 7) << 4;           // frag/P rows are ≡ l16 (mod 8)
    const int rC   = wave * 16 + (lane >> 3);  // commit row (i adds +8): wave-owned
    const int sg   = lane & 7;
    const int swzC = ((lane >> 3) & 7) << 4;   // (rC + i*8) & 7 == (lane>>3) & 7

    // Q B-frags, loaded once (wave = rows n0+wave*16 .. +16)
    bf16x8 qf[2];
    #pragma unroll
    for (int kk = 0; kk < 2; ++kk)
        qf[kk] = ld_frag(
            qbp + (size_t)(b * NSEQ + n0 + wave * 16 + l16) * D_ +
            h * 64 + kk * 32 + quad * 8);

    uint4 kr[2], vr[2];
    #define ATTN_LOAD(j)                                                       \
        {   _Pragma("unroll")                                                  \
            for (int i = 0; i < 2; ++i) {                                      \
                kr[i] = *reinterpret_cast<const uint4*>(                       \
                    kbase + (size_t)((j) * 64 + rC + i * 8) * D_ + sg * 8);    \
                vr[i] = *reinterpret_cast<const uint4*>(                       \
                    vbase + (size_t)(rC + i * 8) * NSEQ + (j) * 64 + sg * 8);  \
            } }
    #define ATTN_COMMIT(buf)                                                   \
        {   _Pragma("unroll")                                                  \
            for (int i = 0; i < 2; ++i) {                                      \
                *reinterpret_cast<uint4*>(reinterpret_cast<char*>(Ks[buf]) +   \
                    (rC + i * 8) * 128 + ((sg * 16) ^ swzC)) = kr[i];          \
                *reinterpret_cast<uint4*>(reinterpret_cast<char*>(Vs[buf]) +   \
                    (rC + i * 8) * 128 + ((sg * 16) ^ swzC)) = vr[i];          \
            } }

    ATTN_LOAD(0)
    ATTN_COMMIT(0)
    ATTN_LOAD(1)
    __syncthreads();

    const f32x4 z = {0.f, 0.f, 0.f, 0.f};
    f32x4 oacc[4] = {z, z, z, z};
    float lacc = 0.f;

    for (int j = 0; j < NSEQ / 64; ++j) {
        const int cur = j & 1;
        const char* Kc = reinterpret_cast<const char*>(Ks[cur]);
        const char* Vc = reinterpret_cast<const char*>(Vs[cur]);
        char*       Pb = reinterpret_cast<char*>(Ks[1 - cur]);  // stale half

        // St = K·Q^T : C[key = mg*16+quad*4+r][qrow = l16]
        f32x4 sacc[4] = {z, z, z, z};
        #pragma unroll
        for (int kk = 0; kk < 2; ++kk)
            #pragma unroll
            for (int mg = 0; mg < 4; ++mg) {
                bf16x8 af = *reinterpret_cast<const bf16x8*>(
                    Kc + (mg * 16 + l16) * 128 + ((kk * 64 + quad * 16) ^ swzF));
                sacc[mg] = __builtin_amdgcn_mfma_f32_16x16x32_bf16(
                    af, qf[kk], sacc[mg], 0, 0, 0);
            }

        // exp (m=0), commit P (4 consecutive keys) into stale K buf, defer l
        {
            float ls = 0.f;
            #pragma unroll
            for (int mg = 0; mg < 4; ++mg) {
                float p0 = __expf(sacc[mg][0]);
                float p1 = __expf(sacc[mg][1]);
                float p2 = __expf(sacc[mg][2]);
                float p3 = __expf(sacc[mg][3]);
                ls += (p0 + p1) + (p2 + p3);
                ushort4 pk = make_ushort4(f2b(p0), f2b(p1), f2b(p2), f2b(p3));
                *reinterpret_cast<ushort4*>(
                    Pb + (wave * 16 + l16) * 128 + ((mg * 32 + quad * 8) ^ swzF)) = pk;
            }
            lacc += ls;
        }
        wave_lds_fence();

        // O^T += V^T·P^T  (P rows are wave-private; reads own rows only)
        #pragma unroll
        for (int kkv = 0; kkv < 2; ++kkv) {
            bf16x8 pf = *reinterpret_cast<const bf16x8*>(
                Pb + (wave * 16 + l16) * 128 + ((kkv * 64 + quad * 16) ^ swzF));
            #pragma unroll
            for (int eg = 0; eg < 4; ++eg) {
                bf16x8 af = *reinterpret_cast<const bf16x8*>(
                    Vc + (eg * 16 + l16) * 128 + ((kkv * 64 + quad * 16) ^ swzF));
                oacc[eg] = __builtin_amdgcn_mfma_f32_16x16x32_bf16(
                    af, pf, oacc[eg], 0, 0, 0);
            }
        }

        if (j < NSEQ / 64 - 1) {
            ATTN_COMMIT(1 - cur)  // tile j+1; overwrites only THIS wave's P rows
            if (j + 2 < NSEQ / 64) ATTN_LOAD(j + 2)
        }
        __syncthreads();                        // single barrier per iter
    }

    // l-reduction across quads (each quad holds a different key subset)
    {
        float s = lacc;
        s += __shfl_xor(s, 16);
        s += __shfl_xor(s, 32);
        float li = 1.0f / s;
        unsigned short* op =
            aob + (size_t)(b * NSEQ + n0 + wave * 16 + l16) * D_ + h * 64 + quad * 4;
        #pragma unroll
        for (int eg = 0; eg < 4; ++eg) {
            ushort4 o = make_ushort4(f2b(oacc[eg][0] * li), f2b(oacc[eg][1] * li),
                                     f2b(oacc[eg][2] * li), f2b(oacc[eg][3] * li));
            *reinterpret_cast<ushort4*>(op + eg * 16) = o;
        }
    }
    #undef ATTN_LOAD
    #undef ATTN_COMMIT
}

// ---------------------------------------------------------------------------
// Output NT-GEMM: Out[m][o] = sum_d aob[m][d] * Wout[o][d]. 8192x512x512.
// 128x64 tile, BK=64, double-buffered LDS, one barrier/iter. fp32 out.
// ---------------------------------------------------------------------------
__global__ __launch_bounds__(256, 2)
void out_gemm(const unsigned short* __restrict__ A,
              const unsigned short* __restrict__ Wo,
              float* __restrict__ Out) {
    const int m0  = blockIdx.x * 128;
    const int no0 = blockIdx.y * 64;
    const int tid = threadIdx.x;
    const int wave = tid >> 6, lane = tid & 63;
    const int quad = lane >> 4, l16 = lane & 15;

    __shared__ unsigned short Ab[2][128][72];
    __shared__ unsigned short Bb[2][64][72];

    const unsigned short* Ap = A + (size_t)m0 * D_;
    const unsigned short* Bp = Wo + (size_t)no0 * D_;

    uint4 aU[4], bU[2];
    #define OUT_LOAD(k0)                                                       \
        {   _Pragma("unroll")                                                  \
            for (int i = 0; i < 4; ++i) {                                      \
                int idx = tid + i * 256;                                       \
                aU[i] = *reinterpret_cast<const uint4*>(                       \
                    Ap + (size_t)(idx >> 3) * D_ + (k0) + (idx & 7) * 8);      \
            }                                                                  \
            _Pragma("unroll")                                                  \
            for (int i = 0; i < 2; ++i) {                                      \
                int idx = tid + i * 256;                                       \
                bU[i] = *reinterpret_cast<const uint4*>(                       \
                    Bp + (size_t)(idx >> 3) * D_ + (k0) + (idx & 7) * 8);      \
            } }
    #define OUT_COMMIT(buf)                                                    \
        {   _Pragma("unroll")                                                  \
            for (int i = 0; i < 4; ++i) {                                      \
                int idx = tid + i * 256;                                       \
                *reinterpret_cast<uint4*>(&Ab[buf][idx >> 3][(idx & 7) * 8]) = aU[i]; \
            }                                                                  \
            _Pragma("unroll")                                                  \
            for (int i = 0; i < 2; ++i) {                                      \
                int idx = tid + i * 256;                                       \
                *reinterpret_cast<uint4*>(&Bb[buf][idx >> 3][(idx & 7) * 8]) = bU[i]; \
            } }

    OUT_LOAD(0)
    OUT_COMMIT(0)
    OUT_LOAD(64)
    __syncthreads();

    const f32x4 z = {0.f, 0.f, 0.f, 0.f};
    f32x4 acc[2][4];
    #pragma unroll
    for (int i = 0; i < 2; ++i)
        #pragma unroll
        for (int j = 0; j < 4; ++j) acc[i][j] = z;

    for (int kt = 0; kt < 8; ++kt) {
        const int cur = kt & 1;
        #pragma unroll
        for (int kk = 0; kk < 2; ++kk) {
            bf16x8 bfr[4];
            #pragma unroll
            for (int nt = 0; nt < 4; ++nt)
                bfr[nt] = ld_frag(&Bb[cur][nt * 16 + l16][kk * 32 + quad * 8]);
            #pragma unroll
            for (int mt = 0; mt < 2; ++mt) {
                bf16x8 af = ld_frag(&Ab[cur][wave * 32 + mt * 16 + l16][kk * 32 + quad * 8]);
                #pragma unroll
                for (int nt = 0; nt < 4; ++nt)
                    acc[mt][nt] = __builtin_amdgcn_mfma_f32_16x16x32_bf16(
                        af, bfr[nt], acc[mt][nt], 0, 0, 0);
            }
        }
        if (kt < 7) {
            OUT_COMMIT(1 - cur)
            if (kt + 2 < 8) OUT_LOAD((kt + 2) * 64)
        }
        __syncthreads();
    }
    #pragma unroll
    for (int mt = 0; mt < 2; ++mt)
        #pragma unroll
        for (int nt = 0; nt < 4; ++nt)
            #pragma unroll
            for (int r = 0; r < 4; ++r)
                Out[(size_t)(m0 + wave * 32 + mt * 16 + quad * 4 + r) * D_ +
                    no0 + nt * 16 + l16] = acc[mt][nt][r];
    #undef OUT_LOAD
    #undef OUT_COMMIT
}

// ---------------------------------------------------------------------------
extern "C" void kernel_launch(void* const* d_in, const int* in_sizes, int n_in,
                              void* d_out, int out_size, void* d_ws, size_t ws_size,
                              hipStream_t stream) {
    const float* keys   = (const float*)d_in[0];
    const float* values = (const float*)d_in[1];
    const float* query  = (const float*)d_in[2];
    const float* Wk     = (const float*)d_in[3];
    const float* Wv     = (const float*)d_in[4];
    const float* Wq     = (const float*)d_in[5];
    const float* Wout   = (const float*)d_in[6];
    float* out = (float*)d_out;

    unsigned short* ws16 = (unsigned short*)d_ws;
    const size_t XN = (size_t)B_ * NSEQ * D_;      // 4,194,304
    const size_t WN = (size_t)H_ * D_ * E_;        // 262,144
    unsigned short* wkt = ws16;                    // [he][d]
    unsigned short* wvt = wkt + WN;
    unsigned short* wqt = wvt + WN;                // pre-scaled by 1/64
    unsigned short* wob = wqt + WN;
    unsigned short* qb  = wob + WN;                // [8192][512], col=h*64+e
    unsigned short* kb  = qb + XN;                 // [8192][512]
    unsigned short* vtb = kb + XN;                 // [b][h][e][n]
    unsigned short* aob = vtb + XN;                // [8192][512] head-concat

    cast_w_kernel<<<dim3(1024, 4), 256, 0, stream>>>(Wk, Wv, Wq, Wout,
                                                     wkt, wvt, wqt, wob);

    proj_gemm<<<dim3(64, 8, 3), 256, 0, stream>>>(
        query, keys, values, wqt, wkt, wvt, qb, kb, vtb);

    attn_kernel<<<dim3(1024), 256, 0, stream>>>(qb, kb, vtb, aob);

    out_gemm<<<dim3(64, 8), 256, 0, stream>>>(aob, wob, out);
}

// Round 2
// 220.752 us; speedup vs baseline: 1.4828x; 1.4828x over previous
//
#include <hip/hip_runtime.h>

// B=4, H=8, Nt=Nc=2048, D=512, E=64, scale = 1/64 folded into Wq at cast.
#define B_   4
#define H_   8
#define NSEQ 2048
#define D_   512
#define E_   64

typedef __bf16 bf16x8 __attribute__((ext_vector_type(8)));
typedef float  f32x4  __attribute__((ext_vector_type(4)));

__device__ __forceinline__ unsigned short f2b(float f) {
    __bf16 h = (__bf16)f;                     // RNE
    return __builtin_bit_cast(unsigned short, h);
}
__device__ __forceinline__ bf16x8 ld_frag(const unsigned short* p) {
    return *reinterpret_cast<const bf16x8*>(p);
}
// wave-private LDS write->read ordering
__device__ __forceinline__ void wave_lds_fence() {
    __asm__ __volatile__("s_waitcnt lgkmcnt(0)" ::: "memory");
}
// async global->LDS, 16B per lane: LDS dest = wave-uniform base + lane*16.
__device__ __forceinline__ void async_copy16(const void* g, const unsigned short* l) {
    __builtin_amdgcn_global_load_lds(
        (const __attribute__((address_space(1))) unsigned int*)g,
        (__attribute__((address_space(3))) unsigned int*)l, 16, 0, 0);
}

// ---------------------------------------------------------------------------
// Cast + transpose W: [H][D][E] fp32 -> [he][d] bf16 (y=0..2); Wout (y=3).
// Wq (y=2) pre-scaled by 1/64 (exact exponent shift).
// ---------------------------------------------------------------------------
__global__ __launch_bounds__(256)
void cast_w_kernel(const float* __restrict__ Wk, const float* __restrict__ Wv,
                   const float* __restrict__ Wq, const float* __restrict__ Wo,
                   unsigned short* __restrict__ okt, unsigned short* __restrict__ ovt,
                   unsigned short* __restrict__ oqt, unsigned short* __restrict__ oo) {
    int idx = blockIdx.x * 256 + threadIdx.x;   // < 262144
    int y = blockIdx.y;
    if (y == 3) { oo[idx] = f2b(Wo[idx]); return; }
    const float* src = y == 0 ? Wk : (y == 1 ? Wv : Wq);
    unsigned short* dst = y == 0 ? okt : (y == 1 ? ovt : oqt);
    float scl = (y == 2) ? 0.015625f : 1.0f;
    int hh = idx >> 15, rem = idx & 32767, d = rem >> 6, e = rem & 63;
    dst[hh * 32768 + e * 512 + d] = f2b(src[idx] * scl);   // [(h*64+e)][d]
}

// ---------------------------------------------------------------------------
// Projection NT-GEMM: C[m][he] = sum_d X[m][d] * Wt[he][d]. 8192x512x512.
// 128x64 tile, BK=64, double-buffered LDS, ONE barrier per K-iter.
// which: 0=Q 1=K 2=V. Fused fp32->bf16 cast of X at commit. (unchanged)
// ---------------------------------------------------------------------------
__global__ __launch_bounds__(256, 2)
void proj_gemm(const float* __restrict__ query, const float* __restrict__ keys,
               const float* __restrict__ values,
               const unsigned short* __restrict__ wqt,
               const unsigned short* __restrict__ wkt,
               const unsigned short* __restrict__ wvt,
               unsigned short* __restrict__ qb, unsigned short* __restrict__ kb,
               unsigned short* __restrict__ vtb) {
    const int m0  = blockIdx.x * 128;
    const int no0 = blockIdx.y * 64;
    const int which = blockIdx.z;
    const int tid = threadIdx.x;
    const int wave = tid >> 6, lane = tid & 63;
    const int quad = lane >> 4, l16 = lane & 15;

    const float* X = which == 0 ? query : (which == 1 ? keys : values);
    const unsigned short* W = which == 0 ? wqt : (which == 1 ? wkt : wvt);

    __shared__ unsigned short Ab[2][128][72];   // 36.9 KB
    __shared__ unsigned short Bb[2][64][72];    // 18.4 KB

    const float* Xp = X + (size_t)m0 * D_;
    const unsigned short* Wp = W + (size_t)no0 * D_;

    float4 aF[8]; uint4 bU[2];
    #define PROJ_LOAD(k0)                                                      \
        {   _Pragma("unroll")                                                  \
            for (int i = 0; i < 8; ++i) {                                      \
                int idx = tid + i * 256;                                       \
                aF[i] = *reinterpret_cast<const float4*>(                      \
                    Xp + (size_t)(idx >> 4) * D_ + (k0) + (idx & 15) * 4);     \
            }                                                                  \
            _Pragma("unroll")                                                  \
            for (int i = 0; i < 2; ++i) {                                      \
                int idx = tid + i * 256;                                       \
                bU[i] = *reinterpret_cast<const uint4*>(                       \
                    Wp + (size_t)(idx >> 3) * D_ + (k0) + (idx & 7) * 8);      \
            } }
    #define PROJ_COMMIT(buf)                                                   \
        {   _Pragma("unroll")                                                  \
            for (int i = 0; i < 8; ++i) {                                      \
                int idx = tid + i * 256;                                       \
                ushort4 o = make_ushort4(f2b(aF[i].x), f2b(aF[i].y),           \
                                         f2b(aF[i].z), f2b(aF[i].w));          \
                *reinterpret_cast<ushort4*>(&Ab[buf][idx >> 4][(idx & 15) * 4]) = o; \
            }                                                                  \
            _Pragma("unroll")                                                  \
            for (int i = 0; i < 2; ++i) {                                      \
                int idx = tid + i * 256;                                       \
                *reinterpret_cast<uint4*>(&Bb[buf][idx >> 3][(idx & 7) * 8]) = bU[i]; \
            } }

    PROJ_LOAD(0)
    PROJ_COMMIT(0)
    PROJ_LOAD(64)
    __syncthreads();

    const f32x4 z = {0.f, 0.f, 0.f, 0.f};
    f32x4 acc[2][4];
    #pragma unroll
    for (int i = 0; i < 2; ++i)
        #pragma unroll
        for (int j = 0; j < 4; ++j) acc[i][j] = z;

    for (int kt = 0; kt < 8; ++kt) {
        const int cur = kt & 1;
        #pragma unroll
        for (int kk = 0; kk < 2; ++kk) {
            bf16x8 bfr[4];
            #pragma unroll
            for (int nt = 0; nt < 4; ++nt)
                bfr[nt] = ld_frag(&Bb[cur][nt * 16 + l16][kk * 32 + quad * 8]);
            #pragma unroll
            for (int mt = 0; mt < 2; ++mt) {
                bf16x8 af = ld_frag(&Ab[cur][wave * 32 + mt * 16 + l16][kk * 32 + quad * 8]);
                #pragma unroll
                for (int nt = 0; nt < 4; ++nt)
                    acc[mt][nt] = __builtin_amdgcn_mfma_f32_16x16x32_bf16(
                        af, bfr[nt], acc[mt][nt], 0, 0, 0);
            }
        }
        if (kt < 7) {
            PROJ_COMMIT(1 - cur)               // tile kt+1 (loaded last iter)
            if (kt + 2 < 8) PROJ_LOAD((kt + 2) * 64)
        }
        __syncthreads();                        // single barrier per iter
    }

    // epilogue: reuse Ab as staging
    if (which != 2) {
        unsigned short (*Os)[72] = reinterpret_cast<unsigned short(*)[72]>(&Ab[0][0][0]);
        #pragma unroll
        for (int mt = 0; mt < 2; ++mt)
            #pragma unroll
            for (int nt = 0; nt < 4; ++nt)
                #pragma unroll
                for (int r = 0; r < 4; ++r)
                    Os[wave * 32 + mt * 16 + quad * 4 + r][nt * 16 + l16] =
                        f2b(acc[mt][nt][r]);
        __syncthreads();
        unsigned short* Y = (which == 0 ? qb : kb);
        #pragma unroll
        for (int i = 0; i < 4; ++i) {           // 128 rows x 8 uint4
            int idx = tid + i * 256;
            int row = idx >> 3, seg = idx & 7;
            *reinterpret_cast<uint4*>(Y + (size_t)(m0 + row) * D_ + no0 + seg * 8) =
                *reinterpret_cast<const uint4*>(&Os[row][seg * 8]);
        }
    } else {
        unsigned short (*Ot)[136] = reinterpret_cast<unsigned short(*)[136]>(&Ab[0][0][0]);
        #pragma unroll
        for (int mt = 0; mt < 2; ++mt)
            #pragma unroll
            for (int nt = 0; nt < 4; ++nt) {
                ushort4 o = make_ushort4(f2b(acc[mt][nt][0]), f2b(acc[mt][nt][1]),
                                         f2b(acc[mt][nt][2]), f2b(acc[mt][nt][3]));
                *reinterpret_cast<ushort4*>(
                    &Ot[nt * 16 + l16][wave * 32 + mt * 16 + quad * 4]) = o;
            }
        __syncthreads();
        const int b = m0 >> 11, nloc = m0 & 2047;
        #pragma unroll
        for (int i = 0; i < 4; ++i) {           // 64 he-rows x 16 uint4
            int idx = tid + i * 256;
            int lhe = idx >> 4, seg = idx & 15;
            int ghe = no0 + lhe;                 // h = ghe>>6, e = ghe&63
            *reinterpret_cast<uint4*>(
                vtb + ((size_t)(b * H_ + (ghe >> 6)) * E_ + (ghe & 63)) * NSEQ +
                nloc + seg * 8) =
                *reinterpret_cast<const uint4*>(&Ot[lhe][seg * 8]);
        }
    }
    #undef PROJ_LOAD
    #undef PROJ_COMMIT
}

// ---------------------------------------------------------------------------
// Flash attention, transposed-S, 64-row Q tiles (grid 1024), K/V double-
// buffered LDS, ONE barrier per 64-key iter. Wave = 16 Q-rows.
//   St = K·Q^T ; P = exp(St) via wave-private LDS ; O^T = V^T·P^T.
// m=0 softmax (|s| bounded by construction), deferred l-reduction.
//
// vs round 1 (which spilled ~300 MB/dispatch of scratch to HBM):
//  - K/V staged with global_load_lds width=16: ZERO staging VGPRs, no commit
//    VALU, loads for tile j+1 in flight across the whole compute of tile j
//    (the barrier's vmcnt(0) drain is the only wait). Scratch now impossible.
//  - Swizzle moved to the GLOBAL source address (linear LDS dest + inverse-
//    swizzled source + swizzled read = same layout round 1 verified).
//  - Dedicated swizzled Ps[64][64] again (no stale-buffer aliasing), all LDS
//    accesses element-typed (clean addrspace inference -> ds_* ops).
//  - LDS = 16+16+8 KiB = 40960 B = 160 KiB/4 exactly -> 4 blocks/CU.
// ---------------------------------------------------------------------------
__global__ __launch_bounds__(256, 4)
void attn_kernel(const unsigned short* __restrict__ qbp,
                 const unsigned short* __restrict__ kbp,
                 const unsigned short* __restrict__ vtbp,
                 unsigned short* __restrict__ aob) {
    const int L = blockIdx.x;
    const int bh = L & 31, qt = L >> 5;      // L%8 pattern -> XCD K/V affinity
    const int b = bh >> 3, h = bh & 7;
    const int n0 = qt * 64;
    const int tid = threadIdx.x;
    const int wave = tid >> 6, lane = tid & 63;
    const int quad = lane >> 4, l16 = lane & 15;

    __shared__ unsigned short Ks[2][4096];   // 16 KiB (dbuf K, 64x64, 128-B rows)
    __shared__ unsigned short Vs[2][4096];   // 16 KiB (dbuf V^T)
    __shared__ unsigned short Ps[4096];      //  8 KiB (wave-private rows)

    const unsigned short* kbase = kbp + (size_t)(b * NSEQ) * D_ + h * 64;
    const unsigned short* vbase = vtbp + (size_t)(b * H_ + h) * E_ * NSEQ;

    const int swzF = (l16 & 7) << 4;   // byte XOR for frag/P rows (row ≡ l16 mod 8)
    const int r8   = lane >> 3;        // staging: lane covers row r8 of an 8-row slab
    const int sg   = lane & 7;         //          16B slot within the 128B row
    const int colK = (sg * 16) ^ ((r8 & 7) << 4);  // pre-swizzled source column
    // lane l writes LDS at (uniform base + l*16) = row(wave*16+i*8+r8), slot sg;
    // sourcing global column colK makes LDS[row][x] = G[row][x ^ ((row&7)<<4)].

    // Q B-frags, loaded once (wave = rows n0+wave*16 .. +16)
    bf16x8 qf[2];
    #pragma unroll
    for (int kk = 0; kk < 2; ++kk)
        qf[kk] = ld_frag(
            qbp + (size_t)(b * NSEQ + n0 + wave * 16 + l16) * D_ +
            h * 64 + kk * 32 + quad * 8);

    #define ATTN_STAGE(j, buf)                                                 \
        {   _Pragma("unroll")                                                  \
            for (int i = 0; i < 2; ++i) {                                      \
                async_copy16(                                                  \
                    (const char*)(kbase +                                      \
                        (size_t)((j) * 64 + wave * 16 + i * 8 + r8) * D_) + colK, \
                    &Ks[buf][wave * 1024 + i * 512]);                          \
                async_copy16(                                                  \
                    (const char*)(vbase +                                      \
                        (size_t)(wave * 16 + i * 8 + r8) * NSEQ + (j) * 64) + colK, \
                    &Vs[buf][wave * 1024 + i * 512]);                          \
            } }

    ATTN_STAGE(0, 0)
    __syncthreads();                            // vmcnt drain: tile 0 resident

    const f32x4 z = {0.f, 0.f, 0.f, 0.f};
    f32x4 oacc[4] = {z, z, z, z};
    float lacc = 0.f;

    for (int j = 0; j < NSEQ / 64; ++j) {
        const int cur = j & 1;
        if (j + 1 < NSEQ / 64) ATTN_STAGE(j + 1, 1 - cur)   // in flight over compute

        // St = K·Q^T : C[key = mg*16+quad*4+r][qrow = l16]
        f32x4 sacc[4] = {z, z, z, z};
        #pragma unroll
        for (int kk = 0; kk < 2; ++kk)
            #pragma unroll
            for (int mg = 0; mg < 4; ++mg) {
                bf16x8 af = ld_frag(&Ks[cur][(mg * 16 + l16) * 64 +
                                             ((((kk * 64 + quad * 16) ^ swzF)) >> 1)]);
                sacc[mg] = __builtin_amdgcn_mfma_f32_16x16x32_bf16(
                    af, qf[kk], sacc[mg], 0, 0, 0);
            }

        // exp (m=0), commit P (4 consecutive keys), defer l
        {
            float ls = 0.f;
            #pragma unroll
            for (int mg = 0; mg < 4; ++mg) {
                float p0 = __expf(sacc[mg][0]);
                float p1 = __expf(sacc[mg][1]);
                float p2 = __expf(sacc[mg][2]);
                float p3 = __expf(sacc[mg][3]);
                ls += (p0 + p1) + (p2 + p3);
                ushort4 pk = make_ushort4(f2b(p0), f2b(p1), f2b(p2), f2b(p3));
                *reinterpret_cast<ushort4*>(
                    &Ps[(wave * 16 + l16) * 64 +
                        ((((mg * 32 + quad * 8) ^ swzF)) >> 1)]) = pk;
            }
            lacc += ls;
        }
        wave_lds_fence();

        // O^T += V^T·P^T  (P rows are wave-private; reads own rows only)
        #pragma unroll
        for (int kkv = 0; kkv < 2; ++kkv) {
            bf16x8 pf = ld_frag(&Ps[(wave * 16 + l16) * 64 +
                                    ((((kkv * 64 + quad * 16) ^ swzF)) >> 1)]);
            #pragma unroll
            for (int eg = 0; eg < 4; ++eg) {
                bf16x8 af = ld_frag(&Vs[cur][(eg * 16 + l16) * 64 +
                                             ((((kkv * 64 + quad * 16) ^ swzF)) >> 1)]);
                oacc[eg] = __builtin_amdgcn_mfma_f32_16x16x32_bf16(
                    af, pf, oacc[eg], 0, 0, 0);
            }
        }

        __syncthreads();   // drains vmcnt (tile j+1 committed) + lgkm; flips buffers
    }

    // l-reduction across quads (each quad holds a different key subset)
    {
        float s = lacc;
        s += __shfl_xor(s, 16);
        s += __shfl_xor(s, 32);
        float li = 1.0f / s;
        unsigned short* op =
            aob + (size_t)(b * NSEQ + n0 + wave * 16 + l16) * D_ + h * 64 + quad * 4;
        #pragma unroll
        for (int eg = 0; eg < 4; ++eg) {
            ushort4 o = make_ushort4(f2b(oacc[eg][0] * li), f2b(oacc[eg][1] * li),
                                     f2b(oacc[eg][2] * li), f2b(oacc[eg][3] * li));
            *reinterpret_cast<ushort4*>(op + eg * 16) = o;
        }
    }
    #undef ATTN_STAGE
}

// ---------------------------------------------------------------------------
// Output NT-GEMM: Out[m][o] = sum_d aob[m][d] * Wout[o][d]. 8192x512x512.
// 128x64 tile, BK=64, double-buffered LDS, one barrier/iter. fp32 out.
// ---------------------------------------------------------------------------
__global__ __launch_bounds__(256, 2)
void out_gemm(const unsigned short* __restrict__ A,
              const unsigned short* __restrict__ Wo,
              float* __restrict__ Out) {
    const int m0  = blockIdx.x * 128;
    const int no0 = blockIdx.y * 64;
    const int tid = threadIdx.x;
    const int wave = tid >> 6, lane = tid & 63;
    const int quad = lane >> 4, l16 = lane & 15;

    __shared__ unsigned short Ab[2][128][72];
    __shared__ unsigned short Bb[2][64][72];

    const unsigned short* Ap = A + (size_t)m0 * D_;
    const unsigned short* Bp = Wo + (size_t)no0 * D_;

    uint4 aU[4], bU[2];
    #define OUT_LOAD(k0)                                                       \
        {   _Pragma("unroll")                                                  \
            for (int i = 0; i < 4; ++i) {                                      \
                int idx = tid + i * 256;                                       \
                aU[i] = *reinterpret_cast<const uint4*>(                       \
                    Ap + (size_t)(idx >> 3) * D_ + (k0) + (idx & 7) * 8);      \
            }                                                                  \
            _Pragma("unroll")                                                  \
            for (int i = 0; i < 2; ++i) {                                      \
                int idx = tid + i * 256;                                       \
                bU[i] = *reinterpret_cast<const uint4*>(                       \
                    Bp + (size_t)(idx >> 3) * D_ + (k0) + (idx & 7) * 8);      \
            } }
    #define OUT_COMMIT(buf)                                                    \
        {   _Pragma("unroll")                                                  \
            for (int i = 0; i < 4; ++i) {                                      \
                int idx = tid + i * 256;                                       \
                *reinterpret_cast<uint4*>(&Ab[buf][idx >> 3][(idx & 7) * 8]) = aU[i]; \
            }                                                                  \
            _Pragma("unroll")                                                  \
            for (int i = 0; i < 2; ++i) {                                      \
                int idx = tid + i * 256;                                       \
                *reinterpret_cast<uint4*>(&Bb[buf][idx >> 3][(idx & 7) * 8]) = bU[i]; \
            } }

    OUT_LOAD(0)
    OUT_COMMIT(0)
    OUT_LOAD(64)
    __syncthreads();

    const f32x4 z = {0.f, 0.f, 0.f, 0.f};
    f32x4 acc[2][4];
    #pragma unroll
    for (int i = 0; i < 2; ++i)
        #pragma unroll
        for (int j = 0; j < 4; ++j) acc[i][j] = z;

    for (int kt = 0; kt < 8; ++kt) {
        const int cur = kt & 1;
        #pragma unroll
        for (int kk = 0; kk < 2; ++kk) {
            bf16x8 bfr[4];
            #pragma unroll
            for (int nt = 0; nt < 4; ++nt)
                bfr[nt] = ld_frag(&Bb[cur][nt * 16 + l16][kk * 32 + quad * 8]);
            #pragma unroll
            for (int mt = 0; mt < 2; ++mt) {
                bf16x8 af = ld_frag(&Ab[cur][wave * 32 + mt * 16 + l16][kk * 32 + quad * 8]);
                #pragma unroll
                for (int nt = 0; nt < 4; ++nt)
                    acc[mt][nt] = __builtin_amdgcn_mfma_f32_16x16x32_bf16(
                        af, bfr[nt], acc[mt][nt], 0, 0, 0);
            }
        }
        if (kt < 7) {
            OUT_COMMIT(1 - cur)
            if (kt + 2 < 8) OUT_LOAD((kt + 2) * 64)
        }
        __syncthreads();
    }
    #pragma unroll
    for (int mt = 0; mt < 2; ++mt)
        #pragma unroll
        for (int nt = 0; nt < 4; ++nt)
            #pragma unroll
            for (int r = 0; r < 4; ++r)
                Out[(size_t)(m0 + wave * 32 + mt * 16 + quad * 4 + r) * D_ +
                    no0 + nt * 16 + l16] = acc[mt][nt][r];
    #undef OUT_LOAD
    #undef OUT_COMMIT
}

// ---------------------------------------------------------------------------
extern "C" void kernel_launch(void* const* d_in, const int* in_sizes, int n_in,
                              void* d_out, int out_size, void* d_ws, size_t ws_size,
                              hipStream_t stream) {
    const float* keys   = (const float*)d_in[0];
    const float* values = (const float*)d_in[1];
    const float* query  = (const float*)d_in[2];
    const float* Wk     = (const float*)d_in[3];
    const float* Wv     = (const float*)d_in[4];
    const float* Wq     = (const float*)d_in[5];
    const float* Wout   = (const float*)d_in[6];
    float* out = (float*)d_out;

    unsigned short* ws16 = (unsigned short*)d_ws;
    const size_t XN = (size_t)B_ * NSEQ * D_;      // 4,194,304
    const size_t WN = (size_t)H_ * D_ * E_;        // 262,144
    unsigned short* wkt = ws16;                    // [he][d]
    unsigned short* wvt = wkt + WN;
    unsigned short* wqt = wvt + WN;                // pre-scaled by 1/64
    unsigned short* wob = wqt + WN;
    unsigned short* qb  = wob + WN;                // [8192][512], col=h*64+e
    unsigned short* kb  = qb + XN;                 // [8192][512]
    unsigned short* vtb = kb + XN;                 // [b][h][e][n]
    unsigned short* aob = vtb + XN;                // [8192][512] head-concat

    cast_w_kernel<<<dim3(1024, 4), 256, 0, stream>>>(Wk, Wv, Wq, Wout,
                                                     wkt, wvt, wqt, wob);

    proj_gemm<<<dim3(64, 8, 3), 256, 0, stream>>>(
        query, keys, values, wqt, wkt, wvt, qb, kb, vtb);

    attn_kernel<<<dim3(1024), 256, 0, stream>>>(qb, kb, vtb, aob);

    out_gemm<<<dim3(64, 8), 256, 0, stream>>>(aob, wob, out);
}

// Round 3
// 190.251 us; speedup vs baseline: 1.7206x; 1.1603x over previous
//
#include <hip/hip_runtime.h>

// B=4, H=8, Nt=Nc=2048, D=512, E=64, scale = 1/64 folded into Wq at cast.
#define B_   4
#define H_   8
#define NSEQ 2048
#define D_   512
#define E_   64

typedef __bf16 bf16x8 __attribute__((ext_vector_type(8)));
typedef float  f32x4  __attribute__((ext_vector_type(4)));

__device__ __forceinline__ unsigned short f2b(float f) {
    __bf16 h = (__bf16)f;                     // RNE
    return __builtin_bit_cast(unsigned short, h);
}
__device__ __forceinline__ bf16x8 ld_frag(const unsigned short* p) {
    return *reinterpret_cast<const bf16x8*>(p);
}
// wave-private LDS write->read ordering
__device__ __forceinline__ void wave_lds_fence() {
    __asm__ __volatile__("s_waitcnt lgkmcnt(0)" ::: "memory");
}
// async global->LDS, 16B per lane: LDS dest = wave-uniform base + lane*16.
__device__ __forceinline__ void async_copy16(const void* g, const unsigned short* l) {
    __builtin_amdgcn_global_load_lds(
        (const __attribute__((address_space(1))) unsigned int*)g,
        (__attribute__((address_space(3))) unsigned int*)l, 16, 0, 0);
}

// ---------------------------------------------------------------------------
// Cast + transpose W: [H][D][E] fp32 -> [he][d] bf16 (y=0..2); Wout (y=3).
// Wq (y=2) pre-scaled by 1/64 (exact exponent shift).
// ---------------------------------------------------------------------------
__global__ __launch_bounds__(256)
void cast_w_kernel(const float* __restrict__ Wk, const float* __restrict__ Wv,
                   const float* __restrict__ Wq, const float* __restrict__ Wo,
                   unsigned short* __restrict__ okt, unsigned short* __restrict__ ovt,
                   unsigned short* __restrict__ oqt, unsigned short* __restrict__ oo) {
    int idx = blockIdx.x * 256 + threadIdx.x;   // < 262144
    int y = blockIdx.y;
    if (y == 3) { oo[idx] = f2b(Wo[idx]); return; }
    const float* src = y == 0 ? Wk : (y == 1 ? Wv : Wq);
    unsigned short* dst = y == 0 ? okt : (y == 1 ? ovt : oqt);
    float scl = (y == 2) ? 0.015625f : 1.0f;
    int hh = idx >> 15, rem = idx & 32767, d = rem >> 6, e = rem & 63;
    dst[hh * 32768 + e * 512 + d] = f2b(src[idx] * scl);   // [(h*64+e)][d]
}

// ---------------------------------------------------------------------------
// X cast: fp32 [8192][512] -> bf16 [8192][512], y selects q/k/v. Pure
// memory-bound (48 MB rd + 24 MB wr ~= 12 us at HBM ceiling). float4 loads.
// ---------------------------------------------------------------------------
__global__ __launch_bounds__(256)
void xcast_kernel(const float* __restrict__ q, const float* __restrict__ k,
                  const float* __restrict__ v,
                  unsigned short* __restrict__ qx, unsigned short* __restrict__ kx,
                  unsigned short* __restrict__ vx) {
    const int y = blockIdx.y;
    const float* src = y == 0 ? q : (y == 1 ? k : v);
    unsigned short* dst = y == 0 ? qx : (y == 1 ? kx : vx);
    #pragma unroll
    for (int i = 0; i < 4; ++i) {
        int e = blockIdx.x * 4096 + i * 1024 + threadIdx.x * 4;
        float4 f = *reinterpret_cast<const float4*>(src + e);
        *reinterpret_cast<ushort4*>(dst + e) =
            make_ushort4(f2b(f.x), f2b(f.y), f2b(f.z), f2b(f.w));
    }
}

// ---------------------------------------------------------------------------
// Projection NT-GEMM (pure bf16): C[m][he] = sum_d X[m][d]*Wt[he][d].
// 8192x512x512, which: 0=Q 1=K 2=V. 128x64 tile, BK=64.
// global_load_lds width=16 staging (zero staging VGPRs), inverse-swizzled
// global source + swizzled ds_read_b128 (involution verified in attn),
// double-buffered, ONE barrier per K-step. LDS 48 KB -> 3 blocks/CU.
// ---------------------------------------------------------------------------
__global__ __launch_bounds__(256, 3)
void proj_gemm(const unsigned short* __restrict__ qx,
               const unsigned short* __restrict__ kx,
               const unsigned short* __restrict__ vx,
               const unsigned short* __restrict__ wqt,
               const unsigned short* __restrict__ wkt,
               const unsigned short* __restrict__ wvt,
               unsigned short* __restrict__ qb, unsigned short* __restrict__ kb,
               unsigned short* __restrict__ vtb) {
    const int m0  = blockIdx.x * 128;
    const int no0 = blockIdx.y * 64;
    const int which = blockIdx.z;
    const int tid = threadIdx.x;
    const int wave = tid >> 6, lane = tid & 63;
    const int quad = lane >> 4, l16 = lane & 15;

    const unsigned short* X = which == 0 ? qx : (which == 1 ? kx : vx);
    const unsigned short* W = which == 0 ? wqt : (which == 1 ? wkt : wvt);

    __shared__ unsigned short Ab[2][8192];   // 2 x 16 KB (128 rows x 128 B)
    __shared__ unsigned short Bb[2][4096];   // 2 x  8 KB ( 64 rows x 128 B)

    const unsigned short* Xp = X + (size_t)m0 * D_;
    const unsigned short* Wp = W + (size_t)no0 * D_;

    const int swzF = (l16 & 7) << 4;          // frag-read byte XOR (row≡l16 mod 8)
    const int r8   = lane >> 3;               // stage: row within 8-row slab
    const int sg   = lane & 7;                // stage: 16B slot in 128B row
    const int colK = (sg * 16) ^ ((r8 & 7) << 4);  // pre-swizzled source byte col

    // A: 128 rows (4 slabs/wave), B: 64 rows (2 slabs/wave)
    #define PROJ_STAGE(kt, buf)                                                \
        {   _Pragma("unroll")                                                  \
            for (int i = 0; i < 4; ++i)                                        \
                async_copy16(                                                  \
                    (const char*)(Xp + (size_t)(wave * 32 + i * 8 + r8) * D_ + \
                                  (kt) * 64) + colK,                           \
                    &Ab[buf][(wave * 32 + i * 8) * 64]);                       \
            _Pragma("unroll")                                                  \
            for (int i = 0; i < 2; ++i)                                        \
                async_copy16(                                                  \
                    (const char*)(Wp + (size_t)(wave * 16 + i * 8 + r8) * D_ + \
                                  (kt) * 64) + colK,                           \
                    &Bb[buf][(wave * 16 + i * 8) * 64]);                       \
        }

    PROJ_STAGE(0, 0)
    __syncthreads();                          // vmcnt drain: tile 0 resident

    const f32x4 z = {0.f, 0.f, 0.f, 0.f};
    f32x4 acc[2][4];
    #pragma unroll
    for (int i = 0; i < 2; ++i)
        #pragma unroll
        for (int j = 0; j < 4; ++j) acc[i][j] = z;

    for (int kt = 0; kt < 8; ++kt) {
        const int cur = kt & 1;
        if (kt + 1 < 8) PROJ_STAGE(kt + 1, 1 - cur)   // in flight over compute
        #pragma unroll
        for (int kk = 0; kk < 2; ++kk) {
            const int co = ((kk * 64 + quad * 16) ^ swzF) >> 1;
            bf16x8 bfr[4];
            #pragma unroll
            for (int nt = 0; nt < 4; ++nt)
                bfr[nt] = ld_frag(&Bb[cur][(nt * 16 + l16) * 64 + co]);
            #pragma unroll
            for (int mt = 0; mt < 2; ++mt) {
                bf16x8 af = ld_frag(&Ab[cur][(wave * 32 + mt * 16 + l16) * 64 + co]);
                #pragma unroll
                for (int nt = 0; nt < 4; ++nt)
                    acc[mt][nt] = __builtin_amdgcn_mfma_f32_16x16x32_bf16(
                        af, bfr[nt], acc[mt][nt], 0, 0, 0);
            }
        }
        __syncthreads();                      // drains vmcnt (tile kt+1) + lgkm
    }

    // epilogue: overlay staging on Ab (32 KB contiguous)
    if (which != 2) {
        unsigned short (*Os)[72] = reinterpret_cast<unsigned short(*)[72]>(&Ab[0][0]);
        #pragma unroll
        for (int mt = 0; mt < 2; ++mt)
            #pragma unroll
            for (int nt = 0; nt < 4; ++nt)
                #pragma unroll
                for (int r = 0; r < 4; ++r)
                    Os[wave * 32 + mt * 16 + quad * 4 + r][nt * 16 + l16] =
                        f2b(acc[mt][nt][r]);
        __syncthreads();
        unsigned short* Y = (which == 0 ? qb : kb);
        #pragma unroll
        for (int i = 0; i < 4; ++i) {           // 128 rows x 8 uint4
            int idx = tid + i * 256;
            int row = idx >> 3, seg = idx & 7;
            *reinterpret_cast<uint4*>(Y + (size_t)(m0 + row) * D_ + no0 + seg * 8) =
                *reinterpret_cast<const uint4*>(&Os[row][seg * 8]);
        }
    } else {
        unsigned short (*Ot)[136] = reinterpret_cast<unsigned short(*)[136]>(&Ab[0][0]);
        #pragma unroll
        for (int mt = 0; mt < 2; ++mt)
            #pragma unroll
            for (int nt = 0; nt < 4; ++nt) {
                ushort4 o = make_ushort4(f2b(acc[mt][nt][0]), f2b(acc[mt][nt][1]),
                                         f2b(acc[mt][nt][2]), f2b(acc[mt][nt][3]));
                *reinterpret_cast<ushort4*>(
                    &Ot[nt * 16 + l16][wave * 32 + mt * 16 + quad * 4]) = o;
            }
        __syncthreads();
        const int b = m0 >> 11, nloc = m0 & 2047;
        #pragma unroll
        for (int i = 0; i < 4; ++i) {           // 64 he-rows x 16 uint4
            int idx = tid + i * 256;
            int lhe = idx >> 4, seg = idx & 15;
            int ghe = no0 + lhe;                 // h = ghe>>6, e = ghe&63
            *reinterpret_cast<uint4*>(
                vtb + ((size_t)(b * H_ + (ghe >> 6)) * E_ + (ghe & 63)) * NSEQ +
                nloc + seg * 8) =
                *reinterpret_cast<const uint4*>(&Ot[lhe][seg * 8]);
        }
    }
    #undef PROJ_STAGE
}

// ---------------------------------------------------------------------------
// Flash attention (UNCHANGED from round 2 — control for this round).
// ---------------------------------------------------------------------------
__global__ __launch_bounds__(256, 4)
void attn_kernel(const unsigned short* __restrict__ qbp,
                 const unsigned short* __restrict__ kbp,
                 const unsigned short* __restrict__ vtbp,
                 unsigned short* __restrict__ aob) {
    const int L = blockIdx.x;
    const int bh = L & 31, qt = L >> 5;      // L%8 pattern -> XCD K/V affinity
    const int b = bh >> 3, h = bh & 7;
    const int n0 = qt * 64;
    const int tid = threadIdx.x;
    const int wave = tid >> 6, lane = tid & 63;
    const int quad = lane >> 4, l16 = lane & 15;

    __shared__ unsigned short Ks[2][4096];   // 16 KiB (dbuf K, 64x64, 128-B rows)
    __shared__ unsigned short Vs[2][4096];   // 16 KiB (dbuf V^T)
    __shared__ unsigned short Ps[4096];      //  8 KiB (wave-private rows)

    const unsigned short* kbase = kbp + (size_t)(b * NSEQ) * D_ + h * 64;
    const unsigned short* vbase = vtbp + (size_t)(b * H_ + h) * E_ * NSEQ;

    const int swzF = (l16 & 7) << 4;   // byte XOR for frag/P rows (row ≡ l16 mod 8)
    const int r8   = lane >> 3;        // staging: lane covers row r8 of an 8-row slab
    const int sg   = lane & 7;         //          16B slot within the 128B row
    const int colK = (sg * 16) ^ ((r8 & 7) << 4);  // pre-swizzled source column

    // Q B-frags, loaded once (wave = rows n0+wave*16 .. +16)
    bf16x8 qf[2];
    #pragma unroll
    for (int kk = 0; kk < 2; ++kk)
        qf[kk] = ld_frag(
            qbp + (size_t)(b * NSEQ + n0 + wave * 16 + l16) * D_ +
            h * 64 + kk * 32 + quad * 8);

    #define ATTN_STAGE(j, buf)                                                 \
        {   _Pragma("unroll")                                                  \
            for (int i = 0; i < 2; ++i) {                                      \
                async_copy16(                                                  \
                    (const char*)(kbase +                                      \
                        (size_t)((j) * 64 + wave * 16 + i * 8 + r8) * D_) + colK, \
                    &Ks[buf][wave * 1024 + i * 512]);                          \
                async_copy16(                                                  \
                    (const char*)(vbase +                                      \
                        (size_t)(wave * 16 + i * 8 + r8) * NSEQ + (j) * 64) + colK, \
                    &Vs[buf][wave * 1024 + i * 512]);                          \
            } }

    ATTN_STAGE(0, 0)
    __syncthreads();                            // vmcnt drain: tile 0 resident

    const f32x4 z = {0.f, 0.f, 0.f, 0.f};
    f32x4 oacc[4] = {z, z, z, z};
    float lacc = 0.f;

    for (int j = 0; j < NSEQ / 64; ++j) {
        const int cur = j & 1;
        if (j + 1 < NSEQ / 64) ATTN_STAGE(j + 1, 1 - cur)   // in flight over compute

        // St = K·Q^T : C[key = mg*16+quad*4+r][qrow = l16]
        f32x4 sacc[4] = {z, z, z, z};
        #pragma unroll
        for (int kk = 0; kk < 2; ++kk)
            #pragma unroll
            for (int mg = 0; mg < 4; ++mg) {
                bf16x8 af = ld_frag(&Ks[cur][(mg * 16 + l16) * 64 +
                                             ((((kk * 64 + quad * 16) ^ swzF)) >> 1)]);
                sacc[mg] = __builtin_amdgcn_mfma_f32_16x16x32_bf16(
                    af, qf[kk], sacc[mg], 0, 0, 0);
            }

        // exp (m=0), commit P (4 consecutive keys), defer l
        {
            float ls = 0.f;
            #pragma unroll
            for (int mg = 0; mg < 4; ++mg) {
                float p0 = __expf(sacc[mg][0]);
                float p1 = __expf(sacc[mg][1]);
                float p2 = __expf(sacc[mg][2]);
                float p3 = __expf(sacc[mg][3]);
                ls += (p0 + p1) + (p2 + p3);
                ushort4 pk = make_ushort4(f2b(p0), f2b(p1), f2b(p2), f2b(p3));
                *reinterpret_cast<ushort4*>(
                    &Ps[(wave * 16 + l16) * 64 +
                        ((((mg * 32 + quad * 8) ^ swzF)) >> 1)]) = pk;
            }
            lacc += ls;
        }
        wave_lds_fence();

        // O^T += V^T·P^T  (P rows are wave-private; reads own rows only)
        #pragma unroll
        for (int kkv = 0; kkv < 2; ++kkv) {
            bf16x8 pf = ld_frag(&Ps[(wave * 16 + l16) * 64 +
                                    ((((kkv * 64 + quad * 16) ^ swzF)) >> 1)]);
            #pragma unroll
            for (int eg = 0; eg < 4; ++eg) {
                bf16x8 af = ld_frag(&Vs[cur][(eg * 16 + l16) * 64 +
                                             ((((kkv * 64 + quad * 16) ^ swzF)) >> 1)]);
                oacc[eg] = __builtin_amdgcn_mfma_f32_16x16x32_bf16(
                    af, pf, oacc[eg], 0, 0, 0);
            }
        }

        __syncthreads();   // drains vmcnt (tile j+1 committed) + lgkm; flips buffers
    }

    // l-reduction across quads (each quad holds a different key subset)
    {
        float s = lacc;
        s += __shfl_xor(s, 16);
        s += __shfl_xor(s, 32);
        float li = 1.0f / s;
        unsigned short* op =
            aob + (size_t)(b * NSEQ + n0 + wave * 16 + l16) * D_ + h * 64 + quad * 4;
        #pragma unroll
        for (int eg = 0; eg < 4; ++eg) {
            ushort4 o = make_ushort4(f2b(oacc[eg][0] * li), f2b(oacc[eg][1] * li),
                                     f2b(oacc[eg][2] * li), f2b(oacc[eg][3] * li));
            *reinterpret_cast<ushort4*>(op + eg * 16) = o;
        }
    }
    #undef ATTN_STAGE
}

// ---------------------------------------------------------------------------
// Output NT-GEMM: Out[m][o] = sum_d aob[m][d] * Wout[o][d]. 8192x512x512.
// Same global_load_lds structure as proj_gemm; fp32 direct-store epilogue.
// ---------------------------------------------------------------------------
__global__ __launch_bounds__(256, 3)
void out_gemm(const unsigned short* __restrict__ A,
              const unsigned short* __restrict__ Wo,
              float* __restrict__ Out) {
    const int m0  = blockIdx.x * 128;
    const int no0 = blockIdx.y * 64;
    const int tid = threadIdx.x;
    const int wave = tid >> 6, lane = tid & 63;
    const int quad = lane >> 4, l16 = lane & 15;

    __shared__ unsigned short Ab[2][8192];
    __shared__ unsigned short Bb[2][4096];

    const unsigned short* Ap = A + (size_t)m0 * D_;
    const unsigned short* Bp = Wo + (size_t)no0 * D_;

    const int swzF = (l16 & 7) << 4;
    const int r8   = lane >> 3;
    const int sg   = lane & 7;
    const int colK = (sg * 16) ^ ((r8 & 7) << 4);

    #define OUT_STAGE(kt, buf)                                                 \
        {   _Pragma("unroll")                                                  \
            for (int i = 0; i < 4; ++i)                                        \
                async_copy16(                                                  \
                    (const char*)(Ap + (size_t)(wave * 32 + i * 8 + r8) * D_ + \
                                  (kt) * 64) + colK,                           \
                    &Ab[buf][(wave * 32 + i * 8) * 64]);                       \
            _Pragma("unroll")                                                  \
            for (int i = 0; i < 2; ++i)                                        \
                async_copy16(                                                  \
                    (const char*)(Bp + (size_t)(wave * 16 + i * 8 + r8) * D_ + \
                                  (kt) * 64) + colK,                           \
                    &Bb[buf][(wave * 16 + i * 8) * 64]);                       \
        }

    OUT_STAGE(0, 0)
    __syncthreads();

    const f32x4 z = {0.f, 0.f, 0.f, 0.f};
    f32x4 acc[2][4];
    #pragma unroll
    for (int i = 0; i < 2; ++i)
        #pragma unroll
        for (int j = 0; j < 4; ++j) acc[i][j] = z;

    for (int kt = 0; kt < 8; ++kt) {
        const int cur = kt & 1;
        if (kt + 1 < 8) OUT_STAGE(kt + 1, 1 - cur)
        #pragma unroll
        for (int kk = 0; kk < 2; ++kk) {
            const int co = ((kk * 64 + quad * 16) ^ swzF) >> 1;
            bf16x8 bfr[4];
            #pragma unroll
            for (int nt = 0; nt < 4; ++nt)
                bfr[nt] = ld_frag(&Bb[cur][(nt * 16 + l16) * 64 + co]);
            #pragma unroll
            for (int mt = 0; mt < 2; ++mt) {
                bf16x8 af = ld_frag(&Ab[cur][(wave * 32 + mt * 16 + l16) * 64 + co]);
                #pragma unroll
                for (int nt = 0; nt < 4; ++nt)
                    acc[mt][nt] = __builtin_amdgcn_mfma_f32_16x16x32_bf16(
                        af, bfr[nt], acc[mt][nt], 0, 0, 0);
            }
        }
        __syncthreads();
    }
    #pragma unroll
    for (int mt = 0; mt < 2; ++mt)
        #pragma unroll
        for (int nt = 0; nt < 4; ++nt)
            #pragma unroll
            for (int r = 0; r < 4; ++r)
                Out[(size_t)(m0 + wave * 32 + mt * 16 + quad * 4 + r) * D_ +
                    no0 + nt * 16 + l16] = acc[mt][nt][r];
    #undef OUT_STAGE
}

// ---------------------------------------------------------------------------
extern "C" void kernel_launch(void* const* d_in, const int* in_sizes, int n_in,
                              void* d_out, int out_size, void* d_ws, size_t ws_size,
                              hipStream_t stream) {
    const float* keys   = (const float*)d_in[0];
    const float* values = (const float*)d_in[1];
    const float* query  = (const float*)d_in[2];
    const float* Wk     = (const float*)d_in[3];
    const float* Wv     = (const float*)d_in[4];
    const float* Wq     = (const float*)d_in[5];
    const float* Wout   = (const float*)d_in[6];
    float* out = (float*)d_out;

    unsigned short* ws16 = (unsigned short*)d_ws;
    const size_t XN = (size_t)B_ * NSEQ * D_;      // 4,194,304
    const size_t WN = (size_t)H_ * D_ * E_;        // 262,144
    unsigned short* wkt = ws16;                    // [he][d]
    unsigned short* wvt = wkt + WN;
    unsigned short* wqt = wvt + WN;                // pre-scaled by 1/64
    unsigned short* wob = wqt + WN;
    unsigned short* qb  = wob + WN;                // [8192][512], col=h*64+e
    unsigned short* kb  = qb + XN;                 // [8192][512]
    unsigned short* vtb = kb + XN;                 // [b][h][e][n]
    unsigned short* aob = vtb + XN;                // [8192][512] head-concat
    unsigned short* qx  = aob + XN;                // bf16 query  [8192][512]
    unsigned short* kx  = qx + XN;                 // bf16 keys   [8192][512]
    unsigned short* vx  = aob;                     // bf16 values ALIASES aob:
                                                   // vx dead after proj; aob
                                                   // written only by attn (later)

    cast_w_kernel<<<dim3(1024, 4), 256, 0, stream>>>(Wk, Wv, Wq, Wout,
                                                     wkt, wvt, wqt, wob);

    xcast_kernel<<<dim3(1024, 3), 256, 0, stream>>>(query, keys, values,
                                                    qx, kx, vx);

    proj_gemm<<<dim3(64, 8, 3), 256, 0, stream>>>(
        qx, kx, vx, wqt, wkt, wvt, qb, kb, vtb);

    attn_kernel<<<dim3(1024), 256, 0, stream>>>(qb, kb, vtb, aob);

    out_gemm<<<dim3(64, 8), 256, 0, stream>>>(aob, wob, out);
}